// Round 13
// baseline (369.706 us; speedup 1.0000x reference)
//
#include <hip/hip_runtime.h>
#include <hip/hip_bf16.h>

#define NN 100000   // nodes
#define NE 500000   // edges
#define FD 128      // input features
#define HD 64       // hidden
#define RR 16       // relations
#define NBASE 30    // bases
#define GG 1000     // graphs
#define CC 10       // classes
#define NGROUP 6250 // NN/16
#define NBLK ((NE + 255) / 256)   // 1954 edge-blocks

// Per-node 64-vectors (hroot_bf, xw_bf, h_bf, y_bf) are stored sigma-order:
// stored[(c&15)*4 + (c>>4)] = true[c] (MFMA C-layout interleave). Wt/w2t have
// contraction dim sigma-permuted to match. out/d_out are TRUE layout.

typedef __attribute__((ext_vector_type(8))) short bf16x8;
typedef __attribute__((ext_vector_type(4))) float f32x4;

__device__ inline unsigned short f2b(float x) {
  __hip_bfloat16 b = __float2bfloat16(x);
  return *reinterpret_cast<unsigned short*>(&b);
}
__device__ inline float b2f(unsigned short u) {
  return __uint_as_float(((unsigned)u) << 16);
}
__device__ inline unsigned pk2(float a, float b) {
  return (unsigned)f2b(a) | ((unsigned)f2b(b) << 16);
}

// ---------------- fused prep: Wt (basis combo, sigma-k) + wcat + w2t ----------------
__global__ void k_prep(const float* comp, const float* bases, const float* w_root,
                       const float* w_rel, const float* w2, unsigned short* Wt,
                       unsigned short* wcat, unsigned short* w2t) {
  int bx = blockIdx.x;
  if (bx < 256) {
    int idx = bx * 256 + threadIdx.x;  // r*4096 + k*64 + n
    int r = idx >> 12, kj = idx & 4095;
    int k = kj >> 6, n = kj & 63;
    float acc = 0.0f;
    for (int b = 0; b < NBASE; ++b)
      acc += comp[r * NBASE + b] * bases[b * 4096 + kj];
    int sk = (k & 15) * 4 + (k >> 4);
    Wt[(r << 12) + n * 64 + sk] = f2b(acc);
  } else {
    int idx = (bx - 256) * 256 + threadIdx.x;
    if (idx < 16384) {
      int n = idx >> 7, k = idx & 127;
      float v = (n < 64) ? w_root[k * 64 + n] : w_rel[k * 64 + (n - 64)];
      wcat[n * 128 + k] = f2b(v);
    } else if (idx < 16384 + 4096) {
      int i2 = idx - 16384;
      int n = i2 >> 6, k = i2 & 63;
      int sk = (k & 15) * 4 + (k >> 4);
      w2t[n * 64 + sk] = f2b(w2[k * 64 + n]);
    }
  }
}

// ---------------- hroot_bf / xw_bf (sigma), 2 waves/group, preloaded x (R11 best) ----------------
__global__ __launch_bounds__(256) void k_proj_mfma(const float* x, const unsigned short* wcat,
                                                   const float* b1, unsigned short* hroot_bf,
                                                   unsigned short* xw_bf) {
  int wv = threadIdx.x >> 6, l = threadIdx.x & 63, m = l & 15, q = l >> 4;
  int gid = blockIdx.x * 4 + wv;
  int g = gid >> 1, half = gid & 1;   // half 0 -> h tiles, half 1 -> xw tiles
  if (g >= NGROUP) return;
  size_t n0 = (size_t)g * 16;
  const float* xr = x + (n0 + m) * FD + q * 8;
  float4 xv[8];
#pragma unroll
  for (int s = 0; s < 4; ++s) {
    xv[2 * s] = *reinterpret_cast<const float4*>(xr + s * 32);
    xv[2 * s + 1] = *reinterpret_cast<const float4*>(xr + s * 32 + 4);
  }
  f32x4 acc[4];
#pragma unroll
  for (int nt = 0; nt < 4; ++nt) acc[nt] = (f32x4){0, 0, 0, 0};
#pragma unroll
  for (int s = 0; s < 4; ++s) {
    float4 xa = xv[2 * s], xb = xv[2 * s + 1];
    bf16x8 a;
    a[0] = (short)f2b(xa.x); a[1] = (short)f2b(xa.y);
    a[2] = (short)f2b(xa.z); a[3] = (short)f2b(xa.w);
    a[4] = (short)f2b(xb.x); a[5] = (short)f2b(xb.y);
    a[6] = (short)f2b(xb.z); a[7] = (short)f2b(xb.w);
#pragma unroll
    for (int nt = 0; nt < 4; ++nt) {
      bf16x8 b = *reinterpret_cast<const bf16x8*>(
          wcat + ((half * 4 + nt) * 16 + m) * 128 + s * 32 + q * 8);
      acc[nt] = __builtin_amdgcn_mfma_f32_16x16x32_bf16(a, b, acc[nt], 0, 0, 0);
    }
  }
  float bv[4] = {0, 0, 0, 0};
  if (half == 0) {
#pragma unroll
    for (int nt = 0; nt < 4; ++nt) bv[nt] = b1[nt * 16 + m];
  }
  unsigned short* dbuf = half ? xw_bf : hroot_bf;
#pragma unroll
  for (int i = 0; i < 4; ++i) {
    size_t row = (n0 + q * 4 + i) * 64 + m * 4;  // sigma: stored = m*4 + nt
    uint2 o;
    o.x = pk2(acc[0][i] + bv[0], acc[1][i] + bv[1]);
    o.y = pk2(acc[2][i] + bv[2], acc[3][i] + bv[3]);
    *reinterpret_cast<uint2*>(dbuf + row) = o;
  }
}

// ---------------- histograms: per-block type counts bch + hist2[dst*16+type] ----------------
__global__ void k_hists(const int* ei, const int* etype, int* bch, int* hist2) {
  __shared__ int lh[RR];
  if (threadIdx.x < RR) lh[threadIdx.x] = 0;
  __syncthreads();
  int e = blockIdx.x * 256 + threadIdx.x;
  if (e < NE) {
    int t = etype[e];
    atomicAdd(&lh[t], 1);
    atomicAdd(&hist2[ei[NE + e] * RR + t], 1);
  }
  __syncthreads();
  if (threadIdx.x < RR) bch[blockIdx.x * RR + threadIdx.x] = lh[threadIdx.x];
}

// ---------------- hierarchical scan of hist2 ----------------
__device__ inline int block_scan_incl(int v, int* ps, int t) {
  ps[t] = v;
  __syncthreads();
  for (int off = 1; off < 256; off <<= 1) {
    int u = (t >= off) ? ps[t - off] : 0;
    __syncthreads();
    ps[t] += u;
    __syncthreads();
  }
  return ps[t];
}

__global__ void k_scanA(const int* hist2, int* bsum) {
  __shared__ int red[256];
  int t = threadIdx.x;
  red[t] = hist2[blockIdx.x * 256 + t];
  __syncthreads();
  for (int s = 128; s; s >>= 1) {
    if (t < s) red[t] += red[t + s];
    __syncthreads();
  }
  if (t == 0) bsum[blockIdx.x] = red[0];
}

__global__ void k_scanB(int* bsum) {
  int t = threadIdx.x;
  int loc[25];
  int s = 0;
  if (t < 250) {
    for (int i = 0; i < 25; ++i) { loc[i] = bsum[t * 25 + i]; s += loc[i]; }
  }
  __shared__ int ps[256];
  int incl = block_scan_incl(s, ps, t);
  int base = incl - s;
  if (t < 250) {
    int run = base;
    for (int i = 0; i < 25; ++i) { int tmp = loc[i]; bsum[t * 25 + i] = run; run += tmp; }
  }
}

// ctr2 packed: low 20 bits = running slot (starts at rowptr), bits 20+ = segment count.
__global__ void k_scanC(const int* hist2, const int* bsum, int* rowptr2, int* ctr2) {
  int t = threadIdx.x;
  int gid = blockIdx.x * 256 + t;
  int v = hist2[gid];
  __shared__ int ps[256];
  int incl = block_scan_incl(v, ps, t);
  int ex = bsum[blockIdx.x] + incl - v;
  rowptr2[gid] = ex;
  ctr2[gid] = ex | (v << 20);
}

// ---------------- bscan: bbase[b][t] per-block type bases; offs; bounds ----------------
__global__ void k_bscan(const int* bch, const int* seq, int* bbase, int* offs, int* bounds) {
  __shared__ int part[16][17], chunkbase[16][17];
  __shared__ int colbase[16];
  __shared__ int ps[256];
  int t = threadIdx.x;
  int ty = t & 15, ck = t >> 4;
  const int CH = (NBLK + 15) / 16;
  int b0 = ck * CH, b1 = min(b0 + CH, NBLK);
  int s = 0;
  for (int b = b0; b < b1; ++b) s += bch[b * 16 + ty];
  part[ck][ty] = s;
  __syncthreads();
  if (t < 16) {
    int run = 0;
    for (int c = 0; c < 16; ++c) { chunkbase[c][t] = run; run += part[c][t]; }
    colbase[t] = run;  // column total
  }
  __syncthreads();
  if (t == 0) {
    int run = 0;
    for (int r = 0; r < RR; ++r) { int v = colbase[r]; offs[r] = run; colbase[r] = run; run += v; }
    offs[RR] = run;
  }
  __syncthreads();
  {
    int run = colbase[ty] + chunkbase[ck][ty];
    for (int b = b0; b < b1; ++b) {
      int v = bch[b * 16 + ty];
      bbase[b * 16 + ty] = run;
      run += v;
    }
  }
  // bounds: inclusive cumsum of seq (1000), 250 threads x 4
  int loc[4];
  int ss = 0;
  if (t < 250) {
    for (int i = 0; i < 4; ++i) { loc[i] = seq[t * 4 + i]; ss += loc[i]; }
  }
  int incl = block_scan_incl(ss, ps, t);
  int base = incl - ss;
  if (t < 250) {
    int run = base;
    for (int i = 0; i < 4; ++i) { run += loc[i]; bounds[t * 4 + i] = run; }
  }
}

// ---------------- sort: no hot atomics, no post-rank barrier ----------------
__global__ void k_sort(const int* ei, const int* etype, const float* enorm,
                       const int* bbase, int* ctr2, uint4* tse, uint2* esen) {
  __shared__ int lcnt[RR];
  if (threadIdx.x < RR) lcnt[threadIdx.x] = 0;
  __syncthreads();
  int e = blockIdx.x * 256 + threadIdx.x;
  if (e >= NE) return;
  int t = etype[e];
  int rank = atomicAdd(&lcnt[t], 1);          // LDS, block-local
  int p = bbase[blockIdx.x * RR + t] + rank;  // deterministic base (cached read)
  int src = ei[e];
  int key = ei[NE + e] * RR + t;
  int old = atomicAdd(&ctr2[key], 1);         // random, low-contention
  int pos = old & 0xFFFFF;
  int cnt = old >> 20;
  float inv = 1.0f / (float)max(cnt, 1);
  esen[pos] = make_uint2((unsigned)src, __float_as_uint(enorm[e]));
  tse[p] = make_uint4((unsigned)src, __float_as_uint(inv), (unsigned)pos, 0u);
}

// ---------------- GraphConv segment-sum: 8 edges/iter, uint4 loads (sigma space) ----------------
__global__ __launch_bounds__(256) void k_gconv_seg(const int* rowptr2, const uint2* esen,
    const unsigned short* xw_bf, const unsigned short* hroot_bf, unsigned short* h_bf) {
  int wv = threadIdx.x >> 6, l = threadIdx.x & 63;
  int c8 = l & 7, eq = l >> 3;   // 8 col-chunks x 8 edge slots
  int dst = blockIdx.x * 4 + wv;
  int lo = rowptr2[dst * RR];
  int hi = (dst == NN - 1) ? NE : rowptr2[(dst + 1) * RR];
  float acc[8] = {0, 0, 0, 0, 0, 0, 0, 0};
  for (int base0 = lo; base0 < hi; base0 += 64) {
    int n = min(64, hi - base0);
    int sv = 0;
    float nv = 0.0f;
    if (l < n) {
      uint2 se = esen[base0 + l];
      sv = (int)se.x;
      nv = __uint_as_float(se.y);
    }
    int k8max = (n + 7) >> 3;
    for (int k8 = 0; k8 < k8max; ++k8) {
      int eid = k8 * 8 + eq;
      int s = __shfl(sv, eid);
      float w = __shfl(nv, eid);
      if (eid < n) {
        uint4 v = *reinterpret_cast<const uint4*>(xw_bf + (size_t)s * 64 + c8 * 8);
        acc[0] += b2f((unsigned short)(v.x & 0xffffu)) * w;
        acc[1] += b2f((unsigned short)(v.x >> 16)) * w;
        acc[2] += b2f((unsigned short)(v.y & 0xffffu)) * w;
        acc[3] += b2f((unsigned short)(v.y >> 16)) * w;
        acc[4] += b2f((unsigned short)(v.z & 0xffffu)) * w;
        acc[5] += b2f((unsigned short)(v.z >> 16)) * w;
        acc[6] += b2f((unsigned short)(v.w & 0xffffu)) * w;
        acc[7] += b2f((unsigned short)(v.w >> 16)) * w;
      }
    }
  }
#pragma unroll
  for (int i = 0; i < 8; ++i) {
    acc[i] += __shfl_xor(acc[i], 8);
    acc[i] += __shfl_xor(acc[i], 16);
    acc[i] += __shfl_xor(acc[i], 32);
  }
  if (l < 8) {
    uint4 hb = *reinterpret_cast<const uint4*>(hroot_bf + (size_t)dst * 64 + l * 8);
    acc[0] += b2f((unsigned short)(hb.x & 0xffffu));
    acc[1] += b2f((unsigned short)(hb.x >> 16));
    acc[2] += b2f((unsigned short)(hb.y & 0xffffu));
    acc[3] += b2f((unsigned short)(hb.y >> 16));
    acc[4] += b2f((unsigned short)(hb.z & 0xffffu));
    acc[5] += b2f((unsigned short)(hb.z >> 16));
    acc[6] += b2f((unsigned short)(hb.w & 0xffffu));
    acc[7] += b2f((unsigned short)(hb.w >> 16));
    uint4 o;
    o.x = pk2(acc[0], acc[1]);
    o.y = pk2(acc[2], acc[3]);
    o.z = pk2(acc[4], acc[5]);
    o.w = pk2(acc[6], acc[7]);
    *reinterpret_cast<uint4*>(h_bf + (size_t)dst * 64 + l * 8) = o;
  }
}

// ---------------- RGCN via MFMA; y rows at dst-ordered slots, sigma uint2 stores ----------------
__global__ __launch_bounds__(256) void k_rgcn_y(const uint4* tse, const int* offs,
    const unsigned short* h_bf, const unsigned short* Wt, unsigned short* y_bf) {
  int r = blockIdx.x;
  int lo = offs[r], hi = offs[r + 1];
  int cnt = hi - lo;
  int wv = threadIdx.x >> 6;
  int l = threadIdx.x & 63;
  int m = l & 15, q = l >> 4;
  int ngroups = (cnt + 15) / 16;
  const unsigned short* Wr = Wt + (r << 12);
  bf16x8 bfr[2][4];
#pragma unroll
  for (int s = 0; s < 2; ++s)
#pragma unroll
    for (int nt = 0; nt < 4; ++nt)
      bfr[s][nt] = *reinterpret_cast<const bf16x8*>(Wr + (nt * 16 + m) * 64 + s * 32 + q * 8);

  for (int g = blockIdx.y * 4 + wv; g < ngroups; g += gridDim.y * 4) {
    int base = lo + g * 16;
    int ne = min(16, hi - base);
    int p = base + ((m < ne) ? m : 0);
    uint4 t4 = tse[p];
    int src = (int)t4.x;
    float inv = __uint_as_float(t4.y);
    int pos = (int)t4.z;
    f32x4 acc[4];
#pragma unroll
    for (int nt = 0; nt < 4; ++nt) acc[nt] = (f32x4){0, 0, 0, 0};
    const unsigned short* hrow = h_bf + (size_t)src * 64 + q * 8;
#pragma unroll
    for (int s = 0; s < 2; ++s) {
      bf16x8 afr = *reinterpret_cast<const bf16x8*>(hrow + s * 32);
#pragma unroll
      for (int nt = 0; nt < 4; ++nt)
        acc[nt] = __builtin_amdgcn_mfma_f32_16x16x32_bf16(afr, bfr[s][nt], acc[nt], 0, 0, 0);
    }
#pragma unroll
    for (int i = 0; i < 4; ++i) {
      int row = q * 4 + i;
      float ir = __shfl(inv, row);
      int pr = __shfl(pos, row);
      if (row < ne) {
        uint2 o;
        o.x = pk2(acc[0][i] * ir, acc[1][i] * ir);
        o.y = pk2(acc[2][i] * ir, acc[3][i] * ir);
        *reinterpret_cast<uint2*>(y_bf + (size_t)pr * 64 + m * 4) = o;
      }
    }
  }
}

// ---------------- fused: out[dst] = h_bf[dst]@w2 + b2 + sum(y rows of dst) ----------------
__global__ __launch_bounds__(256) void k_out(const int* rowptr2, const unsigned short* y_bf,
    const unsigned short* h_bf, const unsigned short* w2t, const float* b2, float* out) {
  __shared__ float ldsC[16][68];   // [dst-in-block][sigma col]
  int wv = threadIdx.x >> 6, l = threadIdx.x & 63;
  int c8 = l & 7, eq = l >> 3;     // 8 col-chunks x 8 row slots
  size_t d0 = (size_t)blockIdx.x * 16;
  for (int dd = 0; dd < 4; ++dd) {
    int dst = (int)d0 + wv * 4 + dd;
    int lo = rowptr2[dst * RR];
    int hi = (dst == NN - 1) ? NE : rowptr2[(dst + 1) * RR];
    float acc[8] = {0, 0, 0, 0, 0, 0, 0, 0};
    for (int row = lo + eq; row < hi; row += 8) {
      uint4 v = *reinterpret_cast<const uint4*>(y_bf + (size_t)row * 64 + c8 * 8);
      acc[0] += b2f((unsigned short)(v.x & 0xffffu));
      acc[1] += b2f((unsigned short)(v.x >> 16));
      acc[2] += b2f((unsigned short)(v.y & 0xffffu));
      acc[3] += b2f((unsigned short)(v.y >> 16));
      acc[4] += b2f((unsigned short)(v.z & 0xffffu));
      acc[5] += b2f((unsigned short)(v.z >> 16));
      acc[6] += b2f((unsigned short)(v.w & 0xffffu));
      acc[7] += b2f((unsigned short)(v.w >> 16));
    }
#pragma unroll
    for (int i = 0; i < 8; ++i) {
      acc[i] += __shfl_xor(acc[i], 8);
      acc[i] += __shfl_xor(acc[i], 16);
      acc[i] += __shfl_xor(acc[i], 32);
    }
    if (l < 8) {
      float4 a0 = {acc[0], acc[1], acc[2], acc[3]};
      float4 a1 = {acc[4], acc[5], acc[6], acc[7]};
      *reinterpret_cast<float4*>(&ldsC[wv * 4 + dd][c8 * 8]) = a0;
      *reinterpret_cast<float4*>(&ldsC[wv * 4 + dd][c8 * 8 + 4]) = a1;
    }
  }
  __syncthreads();
  // phase 2: wave wv owns true cols wv*16 + m; y-sum for that col is at sigma m*4+wv
  int m = l & 15, q = l >> 4, nt = wv;
  float bb = b2[nt * 16 + m];
  f32x4 acc;
#pragma unroll
  for (int i = 0; i < 4; ++i) acc[i] = ldsC[q * 4 + i][m * 4 + nt] + bb;
#pragma unroll
  for (int s = 0; s < 2; ++s) {
    bf16x8 a = *reinterpret_cast<const bf16x8*>(h_bf + (d0 + m) * 64 + s * 32 + q * 8);
    bf16x8 b = *reinterpret_cast<const bf16x8*>(w2t + (nt * 16 + m) * 64 + s * 32 + q * 8);
    acc = __builtin_amdgcn_mfma_f32_16x16x32_bf16(a, b, acc, 0, 0, 0);
  }
#pragma unroll
  for (int i = 0; i < 4; ++i)
    out[(d0 + q * 4 + i) * 64 + nt * 16 + m] = acc[i];   // TRUE layout
}

// ---------------- fused pool + MLP head + log_softmax ----------------
__global__ __launch_bounds__(256) void k_head(const float* x, const float* outn,
    const int* bounds, const float* lin_w, const float* lin_b,
    const float* fc_w, const float* fc_b, float* dout) {
  __shared__ float4 psum[5][48], pmax[5][48];
  __shared__ float gsum[192], gmax[192];
  __shared__ float part[4][64];
  __shared__ float hid[HD], lg[CC], mred[2];
  int g = blockIdx.x, t = threadIdx.x;
  int lo = (g == 0) ? 0 : bounds[g - 1];
  int hi = bounds[g];
  int nn = hi - lo;
  if (t < 240) {
    int c4 = t % 48, ch = t / 48;
    int a = lo + (nn * ch) / 5, b = lo + (nn * (ch + 1)) / 5;
    float4 s = {0, 0, 0, 0};
    float4 mx = {-3.4e38f, -3.4e38f, -3.4e38f, -3.4e38f};
    const float* bp;
    int stride;
    if (c4 < 32) { bp = x + (size_t)a * FD + c4 * 4; stride = FD; }
    else         { bp = outn + (size_t)a * 64 + (c4 - 32) * 4; stride = 64; }
    int n = a;
    for (; n + 4 <= b; n += 4) {
      float4 v0 = *reinterpret_cast<const float4*>(bp);
      float4 v1 = *reinterpret_cast<const float4*>(bp + stride);
      float4 v2 = *reinterpret_cast<const float4*>(bp + 2 * stride);
      float4 v3 = *reinterpret_cast<const float4*>(bp + 3 * stride);
      bp += 4 * stride;
      s.x += v0.x + v1.x + v2.x + v3.x;
      s.y += v0.y + v1.y + v2.y + v3.y;
      s.z += v0.z + v1.z + v2.z + v3.z;
      s.w += v0.w + v1.w + v2.w + v3.w;
      mx.x = fmaxf(fmaxf(fmaxf(mx.x, v0.x), fmaxf(v1.x, v2.x)), v3.x);
      mx.y = fmaxf(fmaxf(fmaxf(mx.y, v0.y), fmaxf(v1.y, v2.y)), v3.y);
      mx.z = fmaxf(fmaxf(fmaxf(mx.z, v0.z), fmaxf(v1.z, v2.z)), v3.z);
      mx.w = fmaxf(fmaxf(fmaxf(mx.w, v0.w), fmaxf(v1.w, v2.w)), v3.w);
    }
    for (; n < b; ++n) {
      float4 v = *reinterpret_cast<const float4*>(bp);
      bp += stride;
      s.x += v.x; s.y += v.y; s.z += v.z; s.w += v.w;
      mx.x = fmaxf(mx.x, v.x); mx.y = fmaxf(mx.y, v.y);
      mx.z = fmaxf(mx.z, v.z); mx.w = fmaxf(mx.w, v.w);
    }
    psum[ch][c4] = s;
    pmax[ch][c4] = mx;
  }
  __syncthreads();
  if (t < 48) {
    float4 s = psum[0][t], m = pmax[0][t];
#pragma unroll
    for (int ch = 1; ch < 5; ++ch) {
      float4 ps = psum[ch][t], pm = pmax[ch][t];
      s.x += ps.x; s.y += ps.y; s.z += ps.z; s.w += ps.w;
      m.x = fmaxf(m.x, pm.x); m.y = fmaxf(m.y, pm.y);
      m.z = fmaxf(m.z, pm.z); m.w = fmaxf(m.w, pm.w);
    }
    gsum[t * 4 + 0] = s.x; gsum[t * 4 + 1] = s.y;
    gsum[t * 4 + 2] = s.z; gsum[t * 4 + 3] = s.w;
    gmax[t * 4 + 0] = m.x; gmax[t * 4 + 1] = m.y;
    gmax[t * 4 + 2] = m.z; gmax[t * 4 + 3] = m.w;
  }
  __syncthreads();
  {
    int o = t & 63, pp = t >> 6;
    float a = 0.0f;
    int k0 = pp * 96;
    for (int k = k0; k < k0 + 96; ++k) {
      float gv = (k < 192) ? gsum[k] : gmax[k - 192];
      a += gv * lin_w[k * 64 + o];
    }
    part[pp][o] = a;
  }
  __syncthreads();
  if (t < HD) {
    float a = lin_b[t] + part[0][t] + part[1][t] + part[2][t] + part[3][t];
    hid[t] = fmaxf(a, 0.0f);
  }
  __syncthreads();
  if (t < CC) {
    float a = fc_b[t];
    for (int k = 0; k < HD; ++k) a += hid[k] * fc_w[k * CC + t];
    lg[t] = a;
  }
  __syncthreads();
  if (t == 0) {
    float mm = lg[0];
#pragma unroll
    for (int i = 1; i < CC; ++i) mm = fmaxf(mm, lg[i]);
    float se = 0.0f;
#pragma unroll
    for (int i = 0; i < CC; ++i) se += __expf(lg[i] - mm);
    mred[0] = mm;
    mred[1] = __logf(se);
  }
  __syncthreads();
  if (t < CC) dout[g * CC + t] = lg[t] - mred[0] - mred[1];
}

extern "C" void kernel_launch(void* const* d_in, const int* in_sizes, int n_in,
                              void* d_out, int out_size, void* d_ws, size_t ws_size,
                              hipStream_t stream) {
  const float* x     = (const float*)d_in[0];
  const int* ei      = (const int*)d_in[1];
  const float* enorm = (const float*)d_in[2];
  const int* etype   = (const int*)d_in[3];
  const int* seq     = (const int*)d_in[4];
  const float* w1_rel  = (const float*)d_in[6];
  const float* w1_root = (const float*)d_in[7];
  const float* b1      = (const float*)d_in[8];
  const float* bases   = (const float*)d_in[9];
  const float* comp    = (const float*)d_in[10];
  const float* w2      = (const float*)d_in[11];
  const float* b2      = (const float*)d_in[12];
  const float* lin_w   = (const float*)d_in[13];
  const float* lin_b   = (const float*)d_in[14];
  const float* fc_w    = (const float*)d_in[15];
  const float* fc_b    = (const float*)d_in[16];
  float* dout = (float*)d_out;

  char* p = (char*)d_ws;
  unsigned short* hroot_bf = (unsigned short*)p; p += (size_t)NN * 64 * 2;  // 12.8 MB
  unsigned short* xw_bf    = (unsigned short*)p; p += (size_t)NN * 64 * 2;  // 12.8 MB
  float* out  = (float*)p;  p += (size_t)NN * 64 * 4;                       // 25.6 MB (ctr2 alias)
  unsigned short* y_bf = (unsigned short*)p; p += (size_t)NE * 64 * 2;      // 64 MB
  unsigned short* h_bf = (unsigned short*)p; p += (size_t)NN * 64 * 2;      // 12.8 MB
  unsigned short* Wt   = (unsigned short*)p; p += (size_t)RR * 4096 * 2;
  unsigned short* wcat = (unsigned short*)p; p += (size_t)128 * 128 * 2;
  unsigned short* w2t  = (unsigned short*)p; p += (size_t)64 * 64 * 2;
  uint4* tse   = (uint4*)p; p += (size_t)NE * 16;       // 8 MB
  uint2* esen  = (uint2*)p; p += (size_t)NE * 8;        // 4 MB
  int* hist2   = (int*)p; p += (size_t)NN * RR * 4;     // 6.4 MB
  int* rowptr2 = (int*)p; p += (size_t)NN * RR * 4;     // 6.4 MB
  int* bch     = (int*)p; p += (size_t)NBLK * RR * 4;   // 125 KB
  int* bbase   = (int*)p; p += (size_t)NBLK * RR * 4;   // 125 KB
  int* bsum    = (int*)p; p += (size_t)NGROUP * 4;
  int* offs    = (int*)p; p += 68;
  int* bounds  = (int*)p; p += (size_t)GG * 4;
  int* ctr2    = (int*)out;  // safe: out first written by k_out (after k_sort)

  hipMemsetAsync(hist2, 0, (size_t)NN * RR * 4, stream);

  hipLaunchKernelGGL(k_prep, dim3(256 + 80), dim3(256), 0, stream,
                     comp, bases, w1_root, w1_rel, w2, Wt, wcat, w2t);
  hipLaunchKernelGGL(k_proj_mfma, dim3((2 * NGROUP + 3) / 4), dim3(256), 0, stream,
                     x, wcat, b1, hroot_bf, xw_bf);
  hipLaunchKernelGGL(k_hists, dim3(NBLK), dim3(256), 0, stream, ei, etype, bch, hist2);
  hipLaunchKernelGGL(k_scanA, dim3(NGROUP), dim3(256), 0, stream, hist2, bsum);
  hipLaunchKernelGGL(k_scanB, dim3(1), dim3(256), 0, stream, bsum);
  hipLaunchKernelGGL(k_scanC, dim3(NGROUP), dim3(256), 0, stream, hist2, bsum, rowptr2, ctr2);
  hipLaunchKernelGGL(k_bscan, dim3(1), dim3(256), 0, stream, bch, seq, bbase, offs, bounds);
  hipLaunchKernelGGL(k_sort, dim3(NBLK), dim3(256), 0, stream,
                     ei, etype, enorm, bbase, ctr2, tse, esen);
  hipLaunchKernelGGL(k_gconv_seg, dim3(NN / 4), dim3(256), 0, stream,
                     rowptr2, esen, xw_bf, hroot_bf, h_bf);
  hipLaunchKernelGGL(k_rgcn_y, dim3(RR, 128), dim3(256), 0, stream,
                     tse, offs, h_bf, Wt, y_bf);
  hipLaunchKernelGGL(k_out, dim3(NN / 16), dim3(256), 0, stream,
                     rowptr2, y_bf, h_bf, w2t, b2, out);
  hipLaunchKernelGGL(k_head, dim3(GG), dim3(256), 0, stream, x, out, bounds,
                     lin_w, lin_b, fc_w, fc_b, dout);
}

// Round 14
// 363.897 us; speedup vs baseline: 1.0160x; 1.0160x over previous
//
#include <hip/hip_runtime.h>
#include <hip/hip_bf16.h>

#define NN 100000   // nodes
#define NE 500000   // edges
#define FD 128      // input features
#define HD 64       // hidden
#define RR 16       // relations
#define NBASE 30    // bases
#define GG 1000     // graphs
#define CC 10       // classes
#define NGROUP 6250 // NN/16
#define NBLK ((NE + 255) / 256)   // 1954 edge-blocks

// Per-node 64-vectors (hroot_bf, xw_bf, h_bf, y_bf) are stored sigma-order:
// stored[(c&15)*4 + (c>>4)] = true[c] (MFMA C-layout interleave). Wt/w2t have
// contraction dim sigma-permuted to match. out/d_out are TRUE layout.

typedef __attribute__((ext_vector_type(8))) short bf16x8;
typedef __attribute__((ext_vector_type(4))) float f32x4;

__device__ inline unsigned short f2b(float x) {
  __hip_bfloat16 b = __float2bfloat16(x);
  return *reinterpret_cast<unsigned short*>(&b);
}
__device__ inline float b2f(unsigned short u) {
  return __uint_as_float(((unsigned)u) << 16);
}
__device__ inline unsigned pk2(float a, float b) {
  return (unsigned)f2b(a) | ((unsigned)f2b(b) << 16);
}

// ---------------- fused prep: Wt (basis combo, sigma-k) + wcat + w2t ----------------
__global__ void k_prep(const float* comp, const float* bases, const float* w_root,
                       const float* w_rel, const float* w2, unsigned short* Wt,
                       unsigned short* wcat, unsigned short* w2t) {
  int bx = blockIdx.x;
  if (bx < 256) {
    int idx = bx * 256 + threadIdx.x;  // r*4096 + k*64 + n
    int r = idx >> 12, kj = idx & 4095;
    int k = kj >> 6, n = kj & 63;
    float acc = 0.0f;
    for (int b = 0; b < NBASE; ++b)
      acc += comp[r * NBASE + b] * bases[b * 4096 + kj];
    int sk = (k & 15) * 4 + (k >> 4);
    Wt[(r << 12) + n * 64 + sk] = f2b(acc);
  } else {
    int idx = (bx - 256) * 256 + threadIdx.x;
    if (idx < 16384) {
      int n = idx >> 7, k = idx & 127;
      float v = (n < 64) ? w_root[k * 64 + n] : w_rel[k * 64 + (n - 64)];
      wcat[n * 128 + k] = f2b(v);
    } else if (idx < 16384 + 4096) {
      int i2 = idx - 16384;
      int n = i2 >> 6, k = i2 & 63;
      int sk = (k & 15) * 4 + (k >> 4);
      w2t[n * 64 + sk] = f2b(w2[k * 64 + n]);
    }
  }
}

// ---------------- hroot_bf / xw_bf (sigma), 2 waves/group, preloaded x (best: R11) ----------------
__global__ __launch_bounds__(256) void k_proj_mfma(const float* x, const unsigned short* wcat,
                                                   const float* b1, unsigned short* hroot_bf,
                                                   unsigned short* xw_bf) {
  int wv = threadIdx.x >> 6, l = threadIdx.x & 63, m = l & 15, q = l >> 4;
  int gid = blockIdx.x * 4 + wv;
  int g = gid >> 1, half = gid & 1;   // half 0 -> h tiles, half 1 -> xw tiles
  if (g >= NGROUP) return;
  size_t n0 = (size_t)g * 16;
  const float* xr = x + (n0 + m) * FD + q * 8;
  float4 xv[8];
#pragma unroll
  for (int s = 0; s < 4; ++s) {
    xv[2 * s] = *reinterpret_cast<const float4*>(xr + s * 32);
    xv[2 * s + 1] = *reinterpret_cast<const float4*>(xr + s * 32 + 4);
  }
  f32x4 acc[4];
#pragma unroll
  for (int nt = 0; nt < 4; ++nt) acc[nt] = (f32x4){0, 0, 0, 0};
#pragma unroll
  for (int s = 0; s < 4; ++s) {
    float4 xa = xv[2 * s], xb = xv[2 * s + 1];
    bf16x8 a;
    a[0] = (short)f2b(xa.x); a[1] = (short)f2b(xa.y);
    a[2] = (short)f2b(xa.z); a[3] = (short)f2b(xa.w);
    a[4] = (short)f2b(xb.x); a[5] = (short)f2b(xb.y);
    a[6] = (short)f2b(xb.z); a[7] = (short)f2b(xb.w);
#pragma unroll
    for (int nt = 0; nt < 4; ++nt) {
      bf16x8 b = *reinterpret_cast<const bf16x8*>(
          wcat + ((half * 4 + nt) * 16 + m) * 128 + s * 32 + q * 8);
      acc[nt] = __builtin_amdgcn_mfma_f32_16x16x32_bf16(a, b, acc[nt], 0, 0, 0);
    }
  }
  float bv[4] = {0, 0, 0, 0};
  if (half == 0) {
#pragma unroll
    for (int nt = 0; nt < 4; ++nt) bv[nt] = b1[nt * 16 + m];
  }
  unsigned short* dbuf = half ? xw_bf : hroot_bf;
#pragma unroll
  for (int i = 0; i < 4; ++i) {
    size_t row = (n0 + q * 4 + i) * 64 + m * 4;  // sigma: stored = m*4 + nt
    uint2 o;
    o.x = pk2(acc[0][i] + bv[0], acc[1][i] + bv[1]);
    o.y = pk2(acc[2][i] + bv[2], acc[3][i] + bv[3]);
    *reinterpret_cast<uint2*>(dbuf + row) = o;
  }
}

// ---------------- histograms: per-block type counts bch + hist2[dst*16+type] ----------------
__global__ void k_hists(const int* ei, const int* etype, int* bch, int* hist2) {
  __shared__ int lh[RR];
  if (threadIdx.x < RR) lh[threadIdx.x] = 0;
  __syncthreads();
  int e = blockIdx.x * 256 + threadIdx.x;
  if (e < NE) {
    int t = etype[e];
    atomicAdd(&lh[t], 1);
    atomicAdd(&hist2[ei[NE + e] * RR + t], 1);
  }
  __syncthreads();
  if (threadIdx.x < RR) bch[blockIdx.x * RR + threadIdx.x] = lh[threadIdx.x];
}

// ---------------- hierarchical scan of hist2 ----------------
__device__ inline int block_scan_incl(int v, int* ps, int t) {
  ps[t] = v;
  __syncthreads();
  for (int off = 1; off < 256; off <<= 1) {
    int u = (t >= off) ? ps[t - off] : 0;
    __syncthreads();
    ps[t] += u;
    __syncthreads();
  }
  return ps[t];
}

__global__ void k_scanA(const int* hist2, int* bsum) {
  __shared__ int red[256];
  int t = threadIdx.x;
  red[t] = hist2[blockIdx.x * 256 + t];
  __syncthreads();
  for (int s = 128; s; s >>= 1) {
    if (t < s) red[t] += red[t + s];
    __syncthreads();
  }
  if (t == 0) bsum[blockIdx.x] = red[0];
}

__global__ void k_scanB(int* bsum) {
  int t = threadIdx.x;
  int loc[25];
  int s = 0;
  if (t < 250) {
    for (int i = 0; i < 25; ++i) { loc[i] = bsum[t * 25 + i]; s += loc[i]; }
  }
  __shared__ int ps[256];
  int incl = block_scan_incl(s, ps, t);
  int base = incl - s;
  if (t < 250) {
    int run = base;
    for (int i = 0; i < 25; ++i) { int tmp = loc[i]; bsum[t * 25 + i] = run; run += tmp; }
  }
}

// ctr2 packed: low 20 bits = running slot (starts at rowptr), bits 20+ = segment count.
__global__ void k_scanC(const int* hist2, const int* bsum, int* rowptr2, int* ctr2) {
  int t = threadIdx.x;
  int gid = blockIdx.x * 256 + t;
  int v = hist2[gid];
  __shared__ int ps[256];
  int incl = block_scan_incl(v, ps, t);
  int ex = bsum[blockIdx.x] + incl - v;
  rowptr2[gid] = ex;
  ctr2[gid] = ex | (v << 20);
}

// ---------------- bscan: bbase[b][t] per-block type bases; offs; bounds ----------------
__global__ void k_bscan(const int* bch, const int* seq, int* bbase, int* offs, int* bounds) {
  __shared__ int part[16][17], chunkbase[16][17];
  __shared__ int colbase[16];
  __shared__ int ps[256];
  int t = threadIdx.x;
  int ty = t & 15, ck = t >> 4;
  const int CH = (NBLK + 15) / 16;
  int b0 = ck * CH, b1 = min(b0 + CH, NBLK);
  int s = 0;
  for (int b = b0; b < b1; ++b) s += bch[b * 16 + ty];
  part[ck][ty] = s;
  __syncthreads();
  if (t < 16) {
    int run = 0;
    for (int c = 0; c < 16; ++c) { chunkbase[c][t] = run; run += part[c][t]; }
    colbase[t] = run;  // column total
  }
  __syncthreads();
  if (t == 0) {
    int run = 0;
    for (int r = 0; r < RR; ++r) { int v = colbase[r]; offs[r] = run; colbase[r] = run; run += v; }
    offs[RR] = run;
  }
  __syncthreads();
  {
    int run = colbase[ty] + chunkbase[ck][ty];
    for (int b = b0; b < b1; ++b) {
      int v = bch[b * 16 + ty];
      bbase[b * 16 + ty] = run;
      run += v;
    }
  }
  // bounds: inclusive cumsum of seq (1000), 250 threads x 4
  int loc[4];
  int ss = 0;
  if (t < 250) {
    for (int i = 0; i < 4; ++i) { loc[i] = seq[t * 4 + i]; ss += loc[i]; }
  }
  int incl = block_scan_incl(ss, ps, t);
  int base = incl - ss;
  if (t < 250) {
    int run = base;
    for (int i = 0; i < 4; ++i) { run += loc[i]; bounds[t * 4 + i] = run; }
  }
}

// ---------------- sort: no hot atomics, no post-rank barrier ----------------
__global__ void k_sort(const int* ei, const int* etype, const float* enorm,
                       const int* bbase, int* ctr2, uint4* tse, uint2* esen) {
  __shared__ int lcnt[RR];
  if (threadIdx.x < RR) lcnt[threadIdx.x] = 0;
  __syncthreads();
  int e = blockIdx.x * 256 + threadIdx.x;
  if (e >= NE) return;
  int t = etype[e];
  int rank = atomicAdd(&lcnt[t], 1);          // LDS, block-local
  int p = bbase[blockIdx.x * RR + t] + rank;  // deterministic base (cached read)
  int src = ei[e];
  int key = ei[NE + e] * RR + t;
  int old = atomicAdd(&ctr2[key], 1);         // random, low-contention
  int pos = old & 0xFFFFF;
  int cnt = old >> 20;
  float inv = 1.0f / (float)max(cnt, 1);
  esen[pos] = make_uint2((unsigned)src, __float_as_uint(enorm[e]));
  tse[p] = make_uint4((unsigned)src, __float_as_uint(inv), (unsigned)pos, 0u);
}

// ---------------- GraphConv segment-sum: 4 edges/iter, uint2 loads (sigma space) ----------------
__global__ __launch_bounds__(256) void k_gconv_seg(const int* rowptr2, const uint2* esen,
    const unsigned short* xw_bf, const unsigned short* hroot_bf, unsigned short* h_bf) {
  int wv = threadIdx.x >> 6, l = threadIdx.x & 63;
  int c4 = l & 15, eq = l >> 4;
  int dst = blockIdx.x * 4 + wv;
  int lo = rowptr2[dst * RR];
  int hi = (dst == NN - 1) ? NE : rowptr2[(dst + 1) * RR];
  float4 acc = {0.0f, 0.0f, 0.0f, 0.0f};
  for (int base0 = lo; base0 < hi; base0 += 64) {
    int n = min(64, hi - base0);
    int sv = 0;
    float nv = 0.0f;
    if (l < n) {
      uint2 se = esen[base0 + l];
      sv = (int)se.x;
      nv = __uint_as_float(se.y);
    }
    int k4max = (n + 3) >> 2;
    for (int k4 = 0; k4 < k4max; ++k4) {
      int eid = k4 * 4 + eq;
      int s = __shfl(sv, eid);
      float w = __shfl(nv, eid);
      if (eid < n) {
        uint2 v = *reinterpret_cast<const uint2*>(xw_bf + (size_t)s * 64 + c4 * 4);
        acc.x += b2f((unsigned short)(v.x & 0xffffu)) * w;
        acc.y += b2f((unsigned short)(v.x >> 16)) * w;
        acc.z += b2f((unsigned short)(v.y & 0xffffu)) * w;
        acc.w += b2f((unsigned short)(v.y >> 16)) * w;
      }
    }
  }
  acc.x += __shfl_xor(acc.x, 16); acc.y += __shfl_xor(acc.y, 16);
  acc.z += __shfl_xor(acc.z, 16); acc.w += __shfl_xor(acc.w, 16);
  acc.x += __shfl_xor(acc.x, 32); acc.y += __shfl_xor(acc.y, 32);
  acc.z += __shfl_xor(acc.z, 32); acc.w += __shfl_xor(acc.w, 32);
  if (l < 16) {
    uint2 hb = *reinterpret_cast<const uint2*>(hroot_bf + (size_t)dst * 64 + l * 4);
    acc.x += b2f((unsigned short)(hb.x & 0xffffu));
    acc.y += b2f((unsigned short)(hb.x >> 16));
    acc.z += b2f((unsigned short)(hb.y & 0xffffu));
    acc.w += b2f((unsigned short)(hb.y >> 16));
    uint2 o;
    o.x = pk2(acc.x, acc.y);
    o.y = pk2(acc.z, acc.w);
    *reinterpret_cast<uint2*>(h_bf + (size_t)dst * 64 + l * 4) = o;
  }
}

// ---------------- RGCN via MFMA; y rows at dst-ordered slots, sigma uint2 stores ----------------
__global__ __launch_bounds__(256) void k_rgcn_y(const uint4* tse, const int* offs,
    const unsigned short* h_bf, const unsigned short* Wt, unsigned short* y_bf) {
  int r = blockIdx.x;
  int lo = offs[r], hi = offs[r + 1];
  int cnt = hi - lo;
  int wv = threadIdx.x >> 6;
  int l = threadIdx.x & 63;
  int m = l & 15, q = l >> 4;
  int ngroups = (cnt + 15) / 16;
  const unsigned short* Wr = Wt + (r << 12);
  bf16x8 bfr[2][4];
#pragma unroll
  for (int s = 0; s < 2; ++s)
#pragma unroll
    for (int nt = 0; nt < 4; ++nt)
      bfr[s][nt] = *reinterpret_cast<const bf16x8*>(Wr + (nt * 16 + m) * 64 + s * 32 + q * 8);

  for (int g = blockIdx.y * 4 + wv; g < ngroups; g += gridDim.y * 4) {
    int base = lo + g * 16;
    int ne = min(16, hi - base);
    int p = base + ((m < ne) ? m : 0);
    uint4 t4 = tse[p];
    int src = (int)t4.x;
    float inv = __uint_as_float(t4.y);
    int pos = (int)t4.z;
    f32x4 acc[4];
#pragma unroll
    for (int nt = 0; nt < 4; ++nt) acc[nt] = (f32x4){0, 0, 0, 0};
    const unsigned short* hrow = h_bf + (size_t)src * 64 + q * 8;
#pragma unroll
    for (int s = 0; s < 2; ++s) {
      bf16x8 afr = *reinterpret_cast<const bf16x8*>(hrow + s * 32);
#pragma unroll
      for (int nt = 0; nt < 4; ++nt)
        acc[nt] = __builtin_amdgcn_mfma_f32_16x16x32_bf16(afr, bfr[s][nt], acc[nt], 0, 0, 0);
    }
#pragma unroll
    for (int i = 0; i < 4; ++i) {
      int row = q * 4 + i;
      float ir = __shfl(inv, row);
      int pr = __shfl(pos, row);
      if (row < ne) {
        uint2 o;
        o.x = pk2(acc[0][i] * ir, acc[1][i] * ir);
        o.y = pk2(acc[2][i] * ir, acc[3][i] * ir);
        *reinterpret_cast<uint2*>(y_bf + (size_t)pr * 64 + m * 4) = o;
      }
    }
  }
}

// ---------------- fused: out[dst] = h_bf[dst]@w2 + b2 + sum(y rows of dst) ----------------
__global__ __launch_bounds__(256) void k_out(const int* rowptr2, const unsigned short* y_bf,
    const unsigned short* h_bf, const unsigned short* w2t, const float* b2, float* out) {
  __shared__ float ldsC[16][68];   // [dst-in-block][sigma col]
  int wv = threadIdx.x >> 6, l = threadIdx.x & 63;
  int c4 = l & 15, eq = l >> 4;
  size_t d0 = (size_t)blockIdx.x * 16;
  for (int dd = 0; dd < 4; ++dd) {
    int dst = (int)d0 + wv * 4 + dd;
    int lo = rowptr2[dst * RR];
    int hi = (dst == NN - 1) ? NE : rowptr2[(dst + 1) * RR];
    float4 acc = {0.0f, 0.0f, 0.0f, 0.0f};
    for (int row = lo + eq; row < hi; row += 4) {
      uint2 v = *reinterpret_cast<const uint2*>(y_bf + (size_t)row * 64 + c4 * 4);
      acc.x += b2f((unsigned short)(v.x & 0xffffu));
      acc.y += b2f((unsigned short)(v.x >> 16));
      acc.z += b2f((unsigned short)(v.y & 0xffffu));
      acc.w += b2f((unsigned short)(v.y >> 16));
    }
    acc.x += __shfl_xor(acc.x, 16); acc.y += __shfl_xor(acc.y, 16);
    acc.z += __shfl_xor(acc.z, 16); acc.w += __shfl_xor(acc.w, 16);
    acc.x += __shfl_xor(acc.x, 32); acc.y += __shfl_xor(acc.y, 32);
    acc.z += __shfl_xor(acc.z, 32); acc.w += __shfl_xor(acc.w, 32);
    if (l < 16)
      *reinterpret_cast<float4*>(&ldsC[wv * 4 + dd][l * 4]) = acc;
  }
  __syncthreads();
  // phase 2: wave wv owns true cols wv*16 + m; y-sum for that col is at sigma m*4+wv
  int m = l & 15, q = l >> 4, nt = wv;
  float bb = b2[nt * 16 + m];
  f32x4 acc;
#pragma unroll
  for (int i = 0; i < 4; ++i) acc[i] = ldsC[q * 4 + i][m * 4 + nt] + bb;
#pragma unroll
  for (int s = 0; s < 2; ++s) {
    bf16x8 a = *reinterpret_cast<const bf16x8*>(h_bf + (d0 + m) * 64 + s * 32 + q * 8);
    bf16x8 b = *reinterpret_cast<const bf16x8*>(w2t + (nt * 16 + m) * 64 + s * 32 + q * 8);
    acc = __builtin_amdgcn_mfma_f32_16x16x32_bf16(a, b, acc, 0, 0, 0);
  }
#pragma unroll
  for (int i = 0; i < 4; ++i)
    out[(d0 + q * 4 + i) * 64 + nt * 16 + m] = acc[i];   // TRUE layout
}

// ---------------- fused pool + MLP head + log_softmax ----------------
__global__ __launch_bounds__(256) void k_head(const float* x, const float* outn,
    const int* bounds, const float* lin_w, const float* lin_b,
    const float* fc_w, const float* fc_b, float* dout) {
  __shared__ float4 psum[5][48], pmax[5][48];
  __shared__ float gsum[192], gmax[192];
  __shared__ float part[4][64];
  __shared__ float hid[HD], lg[CC], mred[2];
  int g = blockIdx.x, t = threadIdx.x;
  int lo = (g == 0) ? 0 : bounds[g - 1];
  int hi = bounds[g];
  int nn = hi - lo;
  if (t < 240) {
    int c4 = t % 48, ch = t / 48;
    int a = lo + (nn * ch) / 5, b = lo + (nn * (ch + 1)) / 5;
    float4 s = {0, 0, 0, 0};
    float4 mx = {-3.4e38f, -3.4e38f, -3.4e38f, -3.4e38f};
    const float* bp;
    int stride;
    if (c4 < 32) { bp = x + (size_t)a * FD + c4 * 4; stride = FD; }
    else         { bp = outn + (size_t)a * 64 + (c4 - 32) * 4; stride = 64; }
    int n = a;
    for (; n + 4 <= b; n += 4) {
      float4 v0 = *reinterpret_cast<const float4*>(bp);
      float4 v1 = *reinterpret_cast<const float4*>(bp + stride);
      float4 v2 = *reinterpret_cast<const float4*>(bp + 2 * stride);
      float4 v3 = *reinterpret_cast<const float4*>(bp + 3 * stride);
      bp += 4 * stride;
      s.x += v0.x + v1.x + v2.x + v3.x;
      s.y += v0.y + v1.y + v2.y + v3.y;
      s.z += v0.z + v1.z + v2.z + v3.z;
      s.w += v0.w + v1.w + v2.w + v3.w;
      mx.x = fmaxf(fmaxf(fmaxf(mx.x, v0.x), fmaxf(v1.x, v2.x)), v3.x);
      mx.y = fmaxf(fmaxf(fmaxf(mx.y, v0.y), fmaxf(v1.y, v2.y)), v3.y);
      mx.z = fmaxf(fmaxf(fmaxf(mx.z, v0.z), fmaxf(v1.z, v2.z)), v3.z);
      mx.w = fmaxf(fmaxf(fmaxf(mx.w, v0.w), fmaxf(v1.w, v2.w)), v3.w);
    }
    for (; n < b; ++n) {
      float4 v = *reinterpret_cast<const float4*>(bp);
      bp += stride;
      s.x += v.x; s.y += v.y; s.z += v.z; s.w += v.w;
      mx.x = fmaxf(mx.x, v.x); mx.y = fmaxf(mx.y, v.y);
      mx.z = fmaxf(mx.z, v.z); mx.w = fmaxf(mx.w, v.w);
    }
    psum[ch][c4] = s;
    pmax[ch][c4] = mx;
  }
  __syncthreads();
  if (t < 48) {
    float4 s = psum[0][t], m = pmax[0][t];
#pragma unroll
    for (int ch = 1; ch < 5; ++ch) {
      float4 ps = psum[ch][t], pm = pmax[ch][t];
      s.x += ps.x; s.y += ps.y; s.z += ps.z; s.w += ps.w;
      m.x = fmaxf(m.x, pm.x); m.y = fmaxf(m.y, pm.y);
      m.z = fmaxf(m.z, pm.z); m.w = fmaxf(m.w, pm.w);
    }
    gsum[t * 4 + 0] = s.x; gsum[t * 4 + 1] = s.y;
    gsum[t * 4 + 2] = s.z; gsum[t * 4 + 3] = s.w;
    gmax[t * 4 + 0] = m.x; gmax[t * 4 + 1] = m.y;
    gmax[t * 4 + 2] = m.z; gmax[t * 4 + 3] = m.w;
  }
  __syncthreads();
  {
    int o = t & 63, pp = t >> 6;
    float a = 0.0f;
    int k0 = pp * 96;
    for (int k = k0; k < k0 + 96; ++k) {
      float gv = (k < 192) ? gsum[k] : gmax[k - 192];
      a += gv * lin_w[k * 64 + o];
    }
    part[pp][o] = a;
  }
  __syncthreads();
  if (t < HD) {
    float a = lin_b[t] + part[0][t] + part[1][t] + part[2][t] + part[3][t];
    hid[t] = fmaxf(a, 0.0f);
  }
  __syncthreads();
  if (t < CC) {
    float a = fc_b[t];
    for (int k = 0; k < HD; ++k) a += hid[k] * fc_w[k * CC + t];
    lg[t] = a;
  }
  __syncthreads();
  if (t == 0) {
    float mm = lg[0];
#pragma unroll
    for (int i = 1; i < CC; ++i) mm = fmaxf(mm, lg[i]);
    float se = 0.0f;
#pragma unroll
    for (int i = 0; i < CC; ++i) se += __expf(lg[i] - mm);
    mred[0] = mm;
    mred[1] = __logf(se);
  }
  __syncthreads();
  if (t < CC) dout[g * CC + t] = lg[t] - mred[0] - mred[1];
}

extern "C" void kernel_launch(void* const* d_in, const int* in_sizes, int n_in,
                              void* d_out, int out_size, void* d_ws, size_t ws_size,
                              hipStream_t stream) {
  const float* x     = (const float*)d_in[0];
  const int* ei      = (const int*)d_in[1];
  const float* enorm = (const float*)d_in[2];
  const int* etype   = (const int*)d_in[3];
  const int* seq     = (const int*)d_in[4];
  const float* w1_rel  = (const float*)d_in[6];
  const float* w1_root = (const float*)d_in[7];
  const float* b1      = (const float*)d_in[8];
  const float* bases   = (const float*)d_in[9];
  const float* comp    = (const float*)d_in[10];
  const float* w2      = (const float*)d_in[11];
  const float* b2      = (const float*)d_in[12];
  const float* lin_w   = (const float*)d_in[13];
  const float* lin_b   = (const float*)d_in[14];
  const float* fc_w    = (const float*)d_in[15];
  const float* fc_b    = (const float*)d_in[16];
  float* dout = (float*)d_out;

  char* p = (char*)d_ws;
  unsigned short* hroot_bf = (unsigned short*)p; p += (size_t)NN * 64 * 2;  // 12.8 MB
  unsigned short* xw_bf    = (unsigned short*)p; p += (size_t)NN * 64 * 2;  // 12.8 MB
  float* out  = (float*)p;  p += (size_t)NN * 64 * 4;                       // 25.6 MB (ctr2 alias)
  unsigned short* y_bf = (unsigned short*)p; p += (size_t)NE * 64 * 2;      // 64 MB
  unsigned short* h_bf = (unsigned short*)p; p += (size_t)NN * 64 * 2;      // 12.8 MB
  unsigned short* Wt   = (unsigned short*)p; p += (size_t)RR * 4096 * 2;
  unsigned short* wcat = (unsigned short*)p; p += (size_t)128 * 128 * 2;
  unsigned short* w2t  = (unsigned short*)p; p += (size_t)64 * 64 * 2;
  uint4* tse   = (uint4*)p; p += (size_t)NE * 16;       // 8 MB
  uint2* esen  = (uint2*)p; p += (size_t)NE * 8;        // 4 MB
  int* hist2   = (int*)p; p += (size_t)NN * RR * 4;     // 6.4 MB
  int* rowptr2 = (int*)p; p += (size_t)NN * RR * 4;     // 6.4 MB
  int* bch     = (int*)p; p += (size_t)NBLK * RR * 4;   // 125 KB
  int* bbase   = (int*)p; p += (size_t)NBLK * RR * 4;   // 125 KB
  int* bsum    = (int*)p; p += (size_t)NGROUP * 4;
  int* offs    = (int*)p; p += 68;
  int* bounds  = (int*)p; p += (size_t)GG * 4;
  int* ctr2    = (int*)out;  // safe: out first written by k_out (after k_sort)

  hipMemsetAsync(hist2, 0, (size_t)NN * RR * 4, stream);

  hipLaunchKernelGGL(k_prep, dim3(256 + 80), dim3(256), 0, stream,
                     comp, bases, w1_root, w1_rel, w2, Wt, wcat, w2t);
  hipLaunchKernelGGL(k_proj_mfma, dim3((2 * NGROUP + 3) / 4), dim3(256), 0, stream,
                     x, wcat, b1, hroot_bf, xw_bf);
  hipLaunchKernelGGL(k_hists, dim3(NBLK), dim3(256), 0, stream, ei, etype, bch, hist2);
  hipLaunchKernelGGL(k_scanA, dim3(NGROUP), dim3(256), 0, stream, hist2, bsum);
  hipLaunchKernelGGL(k_scanB, dim3(1), dim3(256), 0, stream, bsum);
  hipLaunchKernelGGL(k_scanC, dim3(NGROUP), dim3(256), 0, stream, hist2, bsum, rowptr2, ctr2);
  hipLaunchKernelGGL(k_bscan, dim3(1), dim3(256), 0, stream, bch, seq, bbase, offs, bounds);
  hipLaunchKernelGGL(k_sort, dim3(NBLK), dim3(256), 0, stream,
                     ei, etype, enorm, bbase, ctr2, tse, esen);
  hipLaunchKernelGGL(k_gconv_seg, dim3(NN / 4), dim3(256), 0, stream,
                     rowptr2, esen, xw_bf, hroot_bf, h_bf);
  hipLaunchKernelGGL(k_rgcn_y, dim3(RR, 256), dim3(256), 0, stream,
                     tse, offs, h_bf, Wt, y_bf);
  hipLaunchKernelGGL(k_out, dim3(NN / 16), dim3(256), 0, stream,
                     rowptr2, y_bf, h_bf, w2t, b2, out);
  hipLaunchKernelGGL(k_head, dim3(GG), dim3(256), 0, stream, x, out, bounds,
                     lin_w, lin_b, fc_w, fc_b, dout);
}

// Round 15
// 362.071 us; speedup vs baseline: 1.0211x; 1.0050x over previous
//
#include <hip/hip_runtime.h>
#include <hip/hip_bf16.h>

#define NN 100000   // nodes
#define NE 500000   // edges
#define FD 128      // input features
#define HD 64       // hidden
#define RR 16       // relations
#define NBASE 30    // bases
#define GG 1000     // graphs
#define CC 10       // classes
#define NGROUP 6250 // NN/16
#define NBLK ((NE + 255) / 256)   // 1954 edge-blocks

// Per-node 64-vectors (hroot_bf, xw_bf, h_bf, y_bf) are stored sigma-order:
// stored[(c&15)*4 + (c>>4)] = true[c] (MFMA C-layout interleave). Wt/w2t have
// contraction dim sigma-permuted to match. out/d_out are TRUE layout.

typedef __attribute__((ext_vector_type(8))) short bf16x8;
typedef __attribute__((ext_vector_type(4))) float f32x4;

__device__ inline unsigned short f2b(float x) {
  __hip_bfloat16 b = __float2bfloat16(x);
  return *reinterpret_cast<unsigned short*>(&b);
}
__device__ inline float b2f(unsigned short u) {
  return __uint_as_float(((unsigned)u) << 16);
}
__device__ inline unsigned pk2(float a, float b) {
  return (unsigned)f2b(a) | ((unsigned)f2b(b) << 16);
}

// ---------------- fused prep: Wt (basis combo, sigma-k) + wcat + w2t ----------------
__global__ void k_prep(const float* comp, const float* bases, const float* w_root,
                       const float* w_rel, const float* w2, unsigned short* Wt,
                       unsigned short* wcat, unsigned short* w2t) {
  int bx = blockIdx.x;
  if (bx < 256) {
    int idx = bx * 256 + threadIdx.x;  // r*4096 + k*64 + n
    int r = idx >> 12, kj = idx & 4095;
    int k = kj >> 6, n = kj & 63;
    float acc = 0.0f;
    for (int b = 0; b < NBASE; ++b)
      acc += comp[r * NBASE + b] * bases[b * 4096 + kj];
    int sk = (k & 15) * 4 + (k >> 4);
    Wt[(r << 12) + n * 64 + sk] = f2b(acc);
  } else {
    int idx = (bx - 256) * 256 + threadIdx.x;
    if (idx < 16384) {
      int n = idx >> 7, k = idx & 127;
      float v = (n < 64) ? w_root[k * 64 + n] : w_rel[k * 64 + (n - 64)];
      wcat[n * 128 + k] = f2b(v);
    } else if (idx < 16384 + 4096) {
      int i2 = idx - 16384;
      int n = i2 >> 6, k = i2 & 63;
      int sk = (k & 15) * 4 + (k >> 4);
      w2t[n * 64 + sk] = f2b(w2[k * 64 + n]);
    }
  }
}

// ---------------- hroot_bf / xw_bf (sigma), 2 waves/group, preloaded x (best: R11) ----------------
__global__ __launch_bounds__(256) void k_proj_mfma(const float* x, const unsigned short* wcat,
                                                   const float* b1, unsigned short* hroot_bf,
                                                   unsigned short* xw_bf) {
  int wv = threadIdx.x >> 6, l = threadIdx.x & 63, m = l & 15, q = l >> 4;
  int gid = blockIdx.x * 4 + wv;
  int g = gid >> 1, half = gid & 1;   // half 0 -> h tiles, half 1 -> xw tiles
  if (g >= NGROUP) return;
  size_t n0 = (size_t)g * 16;
  const float* xr = x + (n0 + m) * FD + q * 8;
  float4 xv[8];
#pragma unroll
  for (int s = 0; s < 4; ++s) {
    xv[2 * s] = *reinterpret_cast<const float4*>(xr + s * 32);
    xv[2 * s + 1] = *reinterpret_cast<const float4*>(xr + s * 32 + 4);
  }
  f32x4 acc[4];
#pragma unroll
  for (int nt = 0; nt < 4; ++nt) acc[nt] = (f32x4){0, 0, 0, 0};
#pragma unroll
  for (int s = 0; s < 4; ++s) {
    float4 xa = xv[2 * s], xb = xv[2 * s + 1];
    bf16x8 a;
    a[0] = (short)f2b(xa.x); a[1] = (short)f2b(xa.y);
    a[2] = (short)f2b(xa.z); a[3] = (short)f2b(xa.w);
    a[4] = (short)f2b(xb.x); a[5] = (short)f2b(xb.y);
    a[6] = (short)f2b(xb.z); a[7] = (short)f2b(xb.w);
#pragma unroll
    for (int nt = 0; nt < 4; ++nt) {
      bf16x8 b = *reinterpret_cast<const bf16x8*>(
          wcat + ((half * 4 + nt) * 16 + m) * 128 + s * 32 + q * 8);
      acc[nt] = __builtin_amdgcn_mfma_f32_16x16x32_bf16(a, b, acc[nt], 0, 0, 0);
    }
  }
  float bv[4] = {0, 0, 0, 0};
  if (half == 0) {
#pragma unroll
    for (int nt = 0; nt < 4; ++nt) bv[nt] = b1[nt * 16 + m];
  }
  unsigned short* dbuf = half ? xw_bf : hroot_bf;
#pragma unroll
  for (int i = 0; i < 4; ++i) {
    size_t row = (n0 + q * 4 + i) * 64 + m * 4;  // sigma: stored = m*4 + nt
    uint2 o;
    o.x = pk2(acc[0][i] + bv[0], acc[1][i] + bv[1]);
    o.y = pk2(acc[2][i] + bv[2], acc[3][i] + bv[3]);
    *reinterpret_cast<uint2*>(dbuf + row) = o;
  }
}

// ---------------- histograms: per-block type counts bch + hist2[dst*16+type] ----------------
__global__ void k_hists(const int* ei, const int* etype, int* bch, int* hist2) {
  __shared__ int lh[RR];
  if (threadIdx.x < RR) lh[threadIdx.x] = 0;
  __syncthreads();
  int e = blockIdx.x * 256 + threadIdx.x;
  if (e < NE) {
    int t = etype[e];
    atomicAdd(&lh[t], 1);
    atomicAdd(&hist2[ei[NE + e] * RR + t], 1);
  }
  __syncthreads();
  if (threadIdx.x < RR) bch[blockIdx.x * RR + threadIdx.x] = lh[threadIdx.x];
}

// ---------------- hierarchical scan of hist2 ----------------
__device__ inline int block_scan_incl(int v, int* ps, int t) {
  ps[t] = v;
  __syncthreads();
  for (int off = 1; off < 256; off <<= 1) {
    int u = (t >= off) ? ps[t - off] : 0;
    __syncthreads();
    ps[t] += u;
    __syncthreads();
  }
  return ps[t];
}

__global__ void k_scanA(const int* hist2, int* bsum) {
  __shared__ int red[256];
  int t = threadIdx.x;
  red[t] = hist2[blockIdx.x * 256 + t];
  __syncthreads();
  for (int s = 128; s; s >>= 1) {
    if (t < s) red[t] += red[t + s];
    __syncthreads();
  }
  if (t == 0) bsum[blockIdx.x] = red[0];
}

__global__ void k_scanB(int* bsum) {
  int t = threadIdx.x;
  int loc[25];
  int s = 0;
  if (t < 250) {
    for (int i = 0; i < 25; ++i) { loc[i] = bsum[t * 25 + i]; s += loc[i]; }
  }
  __shared__ int ps[256];
  int incl = block_scan_incl(s, ps, t);
  int base = incl - s;
  if (t < 250) {
    int run = base;
    for (int i = 0; i < 25; ++i) { int tmp = loc[i]; bsum[t * 25 + i] = run; run += tmp; }
  }
}

// ctr2 packed: low 20 bits = running slot (starts at rowptr), bits 20+ = segment count.
__global__ void k_scanC(const int* hist2, const int* bsum, int* rowptr2, int* ctr2) {
  int t = threadIdx.x;
  int gid = blockIdx.x * 256 + t;
  int v = hist2[gid];
  __shared__ int ps[256];
  int incl = block_scan_incl(v, ps, t);
  int ex = bsum[blockIdx.x] + incl - v;
  rowptr2[gid] = ex;
  ctr2[gid] = ex | (v << 20);
}

// ---------------- bscan: bbase[b][t] per-block type bases; offs; bounds ----------------
__global__ void k_bscan(const int* bch, const int* seq, int* bbase, int* offs, int* bounds) {
  __shared__ int part[16][17], chunkbase[16][17];
  __shared__ int colbase[16];
  __shared__ int ps[256];
  int t = threadIdx.x;
  int ty = t & 15, ck = t >> 4;
  const int CH = (NBLK + 15) / 16;
  int b0 = ck * CH, b1 = min(b0 + CH, NBLK);
  int s = 0;
  for (int b = b0; b < b1; ++b) s += bch[b * 16 + ty];
  part[ck][ty] = s;
  __syncthreads();
  if (t < 16) {
    int run = 0;
    for (int c = 0; c < 16; ++c) { chunkbase[c][t] = run; run += part[c][t]; }
    colbase[t] = run;  // column total
  }
  __syncthreads();
  if (t == 0) {
    int run = 0;
    for (int r = 0; r < RR; ++r) { int v = colbase[r]; offs[r] = run; colbase[r] = run; run += v; }
    offs[RR] = run;
  }
  __syncthreads();
  {
    int run = colbase[ty] + chunkbase[ck][ty];
    for (int b = b0; b < b1; ++b) {
      int v = bch[b * 16 + ty];
      bbase[b * 16 + ty] = run;
      run += v;
    }
  }
  // bounds: inclusive cumsum of seq (1000), 250 threads x 4
  int loc[4];
  int ss = 0;
  if (t < 250) {
    for (int i = 0; i < 4; ++i) { loc[i] = seq[t * 4 + i]; ss += loc[i]; }
  }
  int incl = block_scan_incl(ss, ps, t);
  int base = incl - ss;
  if (t < 250) {
    int run = base;
    for (int i = 0; i < 4; ++i) { run += loc[i]; bounds[t * 4 + i] = run; }
  }
}

// ---------------- sort: no hot atomics, no post-rank barrier ----------------
__global__ void k_sort(const int* ei, const int* etype, const float* enorm,
                       const int* bbase, int* ctr2, uint4* tse, uint2* esen) {
  __shared__ int lcnt[RR];
  if (threadIdx.x < RR) lcnt[threadIdx.x] = 0;
  __syncthreads();
  int e = blockIdx.x * 256 + threadIdx.x;
  if (e >= NE) return;
  int t = etype[e];
  int rank = atomicAdd(&lcnt[t], 1);          // LDS, block-local
  int p = bbase[blockIdx.x * RR + t] + rank;  // deterministic base (cached read)
  int src = ei[e];
  int key = ei[NE + e] * RR + t;
  int old = atomicAdd(&ctr2[key], 1);         // random, low-contention
  int pos = old & 0xFFFFF;
  int cnt = old >> 20;
  float inv = 1.0f / (float)max(cnt, 1);
  esen[pos] = make_uint2((unsigned)src, __float_as_uint(enorm[e]));
  tse[p] = make_uint4((unsigned)src, __float_as_uint(inv), (unsigned)pos, 0u);
}

// ---------------- GraphConv segment-sum: 4 edges/iter, uint2 loads (sigma space) ----------------
__global__ __launch_bounds__(256) void k_gconv_seg(const int* rowptr2, const uint2* esen,
    const unsigned short* xw_bf, const unsigned short* hroot_bf, unsigned short* h_bf) {
  int wv = threadIdx.x >> 6, l = threadIdx.x & 63;
  int c4 = l & 15, eq = l >> 4;
  int dst = blockIdx.x * 4 + wv;
  int lo = rowptr2[dst * RR];
  int hi = (dst == NN - 1) ? NE : rowptr2[(dst + 1) * RR];
  float4 acc = {0.0f, 0.0f, 0.0f, 0.0f};
  for (int base0 = lo; base0 < hi; base0 += 64) {
    int n = min(64, hi - base0);
    int sv = 0;
    float nv = 0.0f;
    if (l < n) {
      uint2 se = esen[base0 + l];
      sv = (int)se.x;
      nv = __uint_as_float(se.y);
    }
    int k4max = (n + 3) >> 2;
    for (int k4 = 0; k4 < k4max; ++k4) {
      int eid = k4 * 4 + eq;
      int s = __shfl(sv, eid);
      float w = __shfl(nv, eid);
      if (eid < n) {
        uint2 v = *reinterpret_cast<const uint2*>(xw_bf + (size_t)s * 64 + c4 * 4);
        acc.x += b2f((unsigned short)(v.x & 0xffffu)) * w;
        acc.y += b2f((unsigned short)(v.x >> 16)) * w;
        acc.z += b2f((unsigned short)(v.y & 0xffffu)) * w;
        acc.w += b2f((unsigned short)(v.y >> 16)) * w;
      }
    }
  }
  acc.x += __shfl_xor(acc.x, 16); acc.y += __shfl_xor(acc.y, 16);
  acc.z += __shfl_xor(acc.z, 16); acc.w += __shfl_xor(acc.w, 16);
  acc.x += __shfl_xor(acc.x, 32); acc.y += __shfl_xor(acc.y, 32);
  acc.z += __shfl_xor(acc.z, 32); acc.w += __shfl_xor(acc.w, 32);
  if (l < 16) {
    uint2 hb = *reinterpret_cast<const uint2*>(hroot_bf + (size_t)dst * 64 + l * 4);
    acc.x += b2f((unsigned short)(hb.x & 0xffffu));
    acc.y += b2f((unsigned short)(hb.x >> 16));
    acc.z += b2f((unsigned short)(hb.y & 0xffffu));
    acc.w += b2f((unsigned short)(hb.y >> 16));
    uint2 o;
    o.x = pk2(acc.x, acc.y);
    o.y = pk2(acc.z, acc.w);
    *reinterpret_cast<uint2*>(h_bf + (size_t)dst * 64 + l * 4) = o;
  }
}

// ---------------- RGCN via MFMA; y rows at dst-ordered slots, sigma uint2 stores ----------------
__global__ __launch_bounds__(256) void k_rgcn_y(const uint4* tse, const int* offs,
    const unsigned short* h_bf, const unsigned short* Wt, unsigned short* y_bf) {
  int r = blockIdx.x;
  int lo = offs[r], hi = offs[r + 1];
  int cnt = hi - lo;
  int wv = threadIdx.x >> 6;
  int l = threadIdx.x & 63;
  int m = l & 15, q = l >> 4;
  int ngroups = (cnt + 15) / 16;
  const unsigned short* Wr = Wt + (r << 12);
  bf16x8 bfr[2][4];
#pragma unroll
  for (int s = 0; s < 2; ++s)
#pragma unroll
    for (int nt = 0; nt < 4; ++nt)
      bfr[s][nt] = *reinterpret_cast<const bf16x8*>(Wr + (nt * 16 + m) * 64 + s * 32 + q * 8);

  for (int g = blockIdx.y * 4 + wv; g < ngroups; g += gridDim.y * 4) {
    int base = lo + g * 16;
    int ne = min(16, hi - base);
    int p = base + ((m < ne) ? m : 0);
    uint4 t4 = tse[p];
    int src = (int)t4.x;
    float inv = __uint_as_float(t4.y);
    int pos = (int)t4.z;
    f32x4 acc[4];
#pragma unroll
    for (int nt = 0; nt < 4; ++nt) acc[nt] = (f32x4){0, 0, 0, 0};
    const unsigned short* hrow = h_bf + (size_t)src * 64 + q * 8;
#pragma unroll
    for (int s = 0; s < 2; ++s) {
      bf16x8 afr = *reinterpret_cast<const bf16x8*>(hrow + s * 32);
#pragma unroll
      for (int nt = 0; nt < 4; ++nt)
        acc[nt] = __builtin_amdgcn_mfma_f32_16x16x32_bf16(afr, bfr[s][nt], acc[nt], 0, 0, 0);
    }
#pragma unroll
    for (int i = 0; i < 4; ++i) {
      int row = q * 4 + i;
      float ir = __shfl(inv, row);
      int pr = __shfl(pos, row);
      if (row < ne) {
        uint2 o;
        o.x = pk2(acc[0][i] * ir, acc[1][i] * ir);
        o.y = pk2(acc[2][i] * ir, acc[3][i] * ir);
        *reinterpret_cast<uint2*>(y_bf + (size_t)pr * 64 + m * 4) = o;
      }
    }
  }
}

// ---------------- fused: out[dst] = h_bf[dst]@w2 + b2 + sum(y rows of dst) ----------------
__global__ __launch_bounds__(256) void k_out(const int* rowptr2, const unsigned short* y_bf,
    const unsigned short* h_bf, const unsigned short* w2t, const float* b2, float* out) {
  __shared__ float ldsC[16][68];   // [dst-in-block][sigma col]
  int wv = threadIdx.x >> 6, l = threadIdx.x & 63;
  int c4 = l & 15, eq = l >> 4;
  size_t d0 = (size_t)blockIdx.x * 16;
  for (int dd = 0; dd < 4; ++dd) {
    int dst = (int)d0 + wv * 4 + dd;
    int lo = rowptr2[dst * RR];
    int hi = (dst == NN - 1) ? NE : rowptr2[(dst + 1) * RR];
    float4 acc = {0.0f, 0.0f, 0.0f, 0.0f};
    for (int row = lo + eq; row < hi; row += 4) {
      uint2 v = *reinterpret_cast<const uint2*>(y_bf + (size_t)row * 64 + c4 * 4);
      acc.x += b2f((unsigned short)(v.x & 0xffffu));
      acc.y += b2f((unsigned short)(v.x >> 16));
      acc.z += b2f((unsigned short)(v.y & 0xffffu));
      acc.w += b2f((unsigned short)(v.y >> 16));
    }
    acc.x += __shfl_xor(acc.x, 16); acc.y += __shfl_xor(acc.y, 16);
    acc.z += __shfl_xor(acc.z, 16); acc.w += __shfl_xor(acc.w, 16);
    acc.x += __shfl_xor(acc.x, 32); acc.y += __shfl_xor(acc.y, 32);
    acc.z += __shfl_xor(acc.z, 32); acc.w += __shfl_xor(acc.w, 32);
    if (l < 16)
      *reinterpret_cast<float4*>(&ldsC[wv * 4 + dd][l * 4]) = acc;
  }
  __syncthreads();
  // phase 2: wave wv owns true cols wv*16 + m; y-sum for that col is at sigma m*4+wv
  int m = l & 15, q = l >> 4, nt = wv;
  float bb = b2[nt * 16 + m];
  f32x4 acc;
#pragma unroll
  for (int i = 0; i < 4; ++i) acc[i] = ldsC[q * 4 + i][m * 4 + nt] + bb;
#pragma unroll
  for (int s = 0; s < 2; ++s) {
    bf16x8 a = *reinterpret_cast<const bf16x8*>(h_bf + (d0 + m) * 64 + s * 32 + q * 8);
    bf16x8 b = *reinterpret_cast<const bf16x8*>(w2t + (nt * 16 + m) * 64 + s * 32 + q * 8);
    acc = __builtin_amdgcn_mfma_f32_16x16x32_bf16(a, b, acc, 0, 0, 0);
  }
#pragma unroll
  for (int i = 0; i < 4; ++i)
    out[(d0 + q * 4 + i) * 64 + nt * 16 + m] = acc[i];   // TRUE layout
}

// ---------------- fused pool + MLP head + log_softmax ----------------
__global__ __launch_bounds__(256) void k_head(const float* x, const float* outn,
    const int* bounds, const float* lin_w, const float* lin_b,
    const float* fc_w, const float* fc_b, float* dout) {
  __shared__ float4 psum[5][48], pmax[5][48];
  __shared__ float gsum[192], gmax[192];
  __shared__ float part[4][64];
  __shared__ float hid[HD], lg[CC], mred[2];
  int g = blockIdx.x, t = threadIdx.x;
  int lo = (g == 0) ? 0 : bounds[g - 1];
  int hi = bounds[g];
  int nn = hi - lo;
  if (t < 240) {
    int c4 = t % 48, ch = t / 48;
    int a = lo + (nn * ch) / 5, b = lo + (nn * (ch + 1)) / 5;
    float4 s = {0, 0, 0, 0};
    float4 mx = {-3.4e38f, -3.4e38f, -3.4e38f, -3.4e38f};
    const float* bp;
    int stride;
    if (c4 < 32) { bp = x + (size_t)a * FD + c4 * 4; stride = FD; }
    else         { bp = outn + (size_t)a * 64 + (c4 - 32) * 4; stride = 64; }
    int n = a;
    for (; n + 4 <= b; n += 4) {
      float4 v0 = *reinterpret_cast<const float4*>(bp);
      float4 v1 = *reinterpret_cast<const float4*>(bp + stride);
      float4 v2 = *reinterpret_cast<const float4*>(bp + 2 * stride);
      float4 v3 = *reinterpret_cast<const float4*>(bp + 3 * stride);
      bp += 4 * stride;
      s.x += v0.x + v1.x + v2.x + v3.x;
      s.y += v0.y + v1.y + v2.y + v3.y;
      s.z += v0.z + v1.z + v2.z + v3.z;
      s.w += v0.w + v1.w + v2.w + v3.w;
      mx.x = fmaxf(fmaxf(fmaxf(mx.x, v0.x), fmaxf(v1.x, v2.x)), v3.x);
      mx.y = fmaxf(fmaxf(fmaxf(mx.y, v0.y), fmaxf(v1.y, v2.y)), v3.y);
      mx.z = fmaxf(fmaxf(fmaxf(mx.z, v0.z), fmaxf(v1.z, v2.z)), v3.z);
      mx.w = fmaxf(fmaxf(fmaxf(mx.w, v0.w), fmaxf(v1.w, v2.w)), v3.w);
    }
    for (; n < b; ++n) {
      float4 v = *reinterpret_cast<const float4*>(bp);
      bp += stride;
      s.x += v.x; s.y += v.y; s.z += v.z; s.w += v.w;
      mx.x = fmaxf(mx.x, v.x); mx.y = fmaxf(mx.y, v.y);
      mx.z = fmaxf(mx.z, v.z); mx.w = fmaxf(mx.w, v.w);
    }
    psum[ch][c4] = s;
    pmax[ch][c4] = mx;
  }
  __syncthreads();
  if (t < 48) {
    float4 s = psum[0][t], m = pmax[0][t];
#pragma unroll
    for (int ch = 1; ch < 5; ++ch) {
      float4 ps = psum[ch][t], pm = pmax[ch][t];
      s.x += ps.x; s.y += ps.y; s.z += ps.z; s.w += ps.w;
      m.x = fmaxf(m.x, pm.x); m.y = fmaxf(m.y, pm.y);
      m.z = fmaxf(m.z, pm.z); m.w = fmaxf(m.w, pm.w);
    }
    gsum[t * 4 + 0] = s.x; gsum[t * 4 + 1] = s.y;
    gsum[t * 4 + 2] = s.z; gsum[t * 4 + 3] = s.w;
    gmax[t * 4 + 0] = m.x; gmax[t * 4 + 1] = m.y;
    gmax[t * 4 + 2] = m.z; gmax[t * 4 + 3] = m.w;
  }
  __syncthreads();
  {
    int o = t & 63, pp = t >> 6;
    float a = 0.0f;
    int k0 = pp * 96;
    for (int k = k0; k < k0 + 96; ++k) {
      float gv = (k < 192) ? gsum[k] : gmax[k - 192];
      a += gv * lin_w[k * 64 + o];
    }
    part[pp][o] = a;
  }
  __syncthreads();
  if (t < HD) {
    float a = lin_b[t] + part[0][t] + part[1][t] + part[2][t] + part[3][t];
    hid[t] = fmaxf(a, 0.0f);
  }
  __syncthreads();
  if (t < CC) {
    float a = fc_b[t];
    for (int k = 0; k < HD; ++k) a += hid[k] * fc_w[k * CC + t];
    lg[t] = a;
  }
  __syncthreads();
  if (t == 0) {
    float mm = lg[0];
#pragma unroll
    for (int i = 1; i < CC; ++i) mm = fmaxf(mm, lg[i]);
    float se = 0.0f;
#pragma unroll
    for (int i = 0; i < CC; ++i) se += __expf(lg[i] - mm);
    mred[0] = mm;
    mred[1] = __logf(se);
  }
  __syncthreads();
  if (t < CC) dout[g * CC + t] = lg[t] - mred[0] - mred[1];
}

extern "C" void kernel_launch(void* const* d_in, const int* in_sizes, int n_in,
                              void* d_out, int out_size, void* d_ws, size_t ws_size,
                              hipStream_t stream) {
  const float* x     = (const float*)d_in[0];
  const int* ei      = (const int*)d_in[1];
  const float* enorm = (const float*)d_in[2];
  const int* etype   = (const int*)d_in[3];
  const int* seq     = (const int*)d_in[4];
  const float* w1_rel  = (const float*)d_in[6];
  const float* w1_root = (const float*)d_in[7];
  const float* b1      = (const float*)d_in[8];
  const float* bases   = (const float*)d_in[9];
  const float* comp    = (const float*)d_in[10];
  const float* w2      = (const float*)d_in[11];
  const float* b2      = (const float*)d_in[12];
  const float* lin_w   = (const float*)d_in[13];
  const float* lin_b   = (const float*)d_in[14];
  const float* fc_w    = (const float*)d_in[15];
  const float* fc_b    = (const float*)d_in[16];
  float* dout = (float*)d_out;

  char* p = (char*)d_ws;
  unsigned short* hroot_bf = (unsigned short*)p; p += (size_t)NN * 64 * 2;  // 12.8 MB
  unsigned short* xw_bf    = (unsigned short*)p; p += (size_t)NN * 64 * 2;  // 12.8 MB
  float* out  = (float*)p;  p += (size_t)NN * 64 * 4;                       // 25.6 MB (ctr2 alias)
  unsigned short* y_bf = (unsigned short*)p; p += (size_t)NE * 64 * 2;      // 64 MB
  unsigned short* h_bf = (unsigned short*)p; p += (size_t)NN * 64 * 2;      // 12.8 MB
  unsigned short* Wt   = (unsigned short*)p; p += (size_t)RR * 4096 * 2;
  unsigned short* wcat = (unsigned short*)p; p += (size_t)128 * 128 * 2;
  unsigned short* w2t  = (unsigned short*)p; p += (size_t)64 * 64 * 2;
  uint4* tse   = (uint4*)p; p += (size_t)NE * 16;       // 8 MB
  uint2* esen  = (uint2*)p; p += (size_t)NE * 8;        // 4 MB
  int* hist2   = (int*)p; p += (size_t)NN * RR * 4;     // 6.4 MB
  int* rowptr2 = (int*)p; p += (size_t)NN * RR * 4;     // 6.4 MB
  int* bch     = (int*)p; p += (size_t)NBLK * RR * 4;   // 125 KB
  int* bbase   = (int*)p; p += (size_t)NBLK * RR * 4;   // 125 KB
  int* bsum    = (int*)p; p += (size_t)NGROUP * 4;
  int* offs    = (int*)p; p += 68;
  int* bounds  = (int*)p; p += (size_t)GG * 4;
  int* ctr2    = (int*)out;  // safe: out first written by k_out (after k_sort)

  hipMemsetAsync(hist2, 0, (size_t)NN * RR * 4, stream);

  hipLaunchKernelGGL(k_prep, dim3(256 + 80), dim3(256), 0, stream,
                     comp, bases, w1_root, w1_rel, w2, Wt, wcat, w2t);
  hipLaunchKernelGGL(k_proj_mfma, dim3((2 * NGROUP + 3) / 4), dim3(256), 0, stream,
                     x, wcat, b1, hroot_bf, xw_bf);
  hipLaunchKernelGGL(k_hists, dim3(NBLK), dim3(256), 0, stream, ei, etype, bch, hist2);
  hipLaunchKernelGGL(k_scanA, dim3(NGROUP), dim3(256), 0, stream, hist2, bsum);
  hipLaunchKernelGGL(k_scanB, dim3(1), dim3(256), 0, stream, bsum);
  hipLaunchKernelGGL(k_scanC, dim3(NGROUP), dim3(256), 0, stream, hist2, bsum, rowptr2, ctr2);
  hipLaunchKernelGGL(k_bscan, dim3(1), dim3(256), 0, stream, bch, seq, bbase, offs, bounds);
  hipLaunchKernelGGL(k_sort, dim3(NBLK), dim3(256), 0, stream,
                     ei, etype, enorm, bbase, ctr2, tse, esen);
  hipLaunchKernelGGL(k_gconv_seg, dim3(NN / 4), dim3(256), 0, stream,
                     rowptr2, esen, xw_bf, hroot_bf, h_bf);
  hipLaunchKernelGGL(k_rgcn_y, dim3(RR, 128), dim3(256), 0, stream,
                     tse, offs, h_bf, Wt, y_bf);
  hipLaunchKernelGGL(k_out, dim3(NN / 16), dim3(256), 0, stream,
                     rowptr2, y_bf, h_bf, w2t, b2, out);
  hipLaunchKernelGGL(k_head, dim3(GG), dim3(256), 0, stream, x, out, bounds,
                     lin_w, lin_b, fc_w, fc_b, dout);
}